// Round 7
// baseline (223.731 us; speedup 1.0000x reference)
//
#include <hip/hip_runtime.h>

#define EMBED 1024
#define NHEAD 16
#define HDIM  64
#define BB    2
#define SS    2048

typedef __bf16 bf16x8 __attribute__((ext_vector_type(8)));
typedef float  f32x4  __attribute__((ext_vector_type(4)));
typedef _Float16 f16x4 __attribute__((ext_vector_type(4)));
typedef _Float16 f16x8 __attribute__((ext_vector_type(8)));
typedef __fp16 hf16x2 __attribute__((ext_vector_type(2)));

#if defined(__has_builtin)
#if __has_builtin(__builtin_amdgcn_exp2f)
#define EXP2(x) __builtin_amdgcn_exp2f(x)
#else
#define EXP2(x) exp2f(x)
#endif
#else
#define EXP2(x) exp2f(x)
#endif

__device__ __forceinline__ unsigned short f2bf(float f) {
  union { float f; unsigned u; } v; v.f = f;
  unsigned r = v.u + 0x7fffu + ((v.u >> 16) & 1u);
  return (unsigned short)(r >> 16);
}

__device__ __forceinline__ float bf2f(unsigned short u) {
  union { unsigned u; float f; } v; v.u = ((unsigned)u) << 16;
  return v.f;
}

__device__ __forceinline__ unsigned short f2h(float f) {
  union { _Float16 h; unsigned short u; } t;
  t.h = (_Float16)f;
  return t.u;
}

__device__ __forceinline__ void g2l16(const unsigned short* g, unsigned short* l) {
  __builtin_amdgcn_global_load_lds(
      (const __attribute__((address_space(1))) unsigned int*)g,
      (__attribute__((address_space(3))) unsigned int*)l, 16, 0, 0);
}

// ------- fused fp32->bf16 convert of x + 4 weights, + maskbias build -------
__global__ __launch_bounds__(256)
void cvt5_kernel(const float* __restrict__ x,  const float* __restrict__ Wq,
                 const float* __restrict__ Wk, const float* __restrict__ Wv,
                 const float* __restrict__ Wo, const int* __restrict__ mask,
                 unsigned short* __restrict__ xb,  unsigned short* __restrict__ Wqb,
                 unsigned short* __restrict__ Wkb, unsigned short* __restrict__ Wvb,
                 unsigned short* __restrict__ Wob, float* __restrict__ mbias) {
  const int i = blockIdx.x * 256 + threadIdx.x;
  if (i < (1 << 21)) {
    const float* src;
    unsigned short* dst;
    int j;
    if (i < (1 << 20)) {
      src = x; dst = xb; j = i;
    } else {
      const int t = i - (1 << 20);
      const int r = t >> 18;
      j = t & ((1 << 18) - 1);
      src = (r == 0) ? Wq : (r == 1) ? Wk : (r == 2) ? Wv : Wo;
      dst = (r == 0) ? Wqb : (r == 1) ? Wkb : (r == 2) ? Wvb : Wob;
    }
    const float4 f = ((const float4*)src)[j];
    ushort4 u;
    u.x = f2bf(f.x); u.y = f2bf(f.y); u.z = f2bf(f.z); u.w = f2bf(f.w);
    ((ushort4*)dst)[j] = u;
  } else {
    const int j = i - (1 << 21);  // 0..1023 int4 groups of mask
    const int4 m = ((const int4*)mask)[j];
    float4 o;
    o.x = m.x ? 0.f : -1e30f; o.y = m.y ? 0.f : -1e30f;
    o.z = m.z ? 0.f : -1e30f; o.w = m.w ? 0.f : -1e30f;
    ((float4*)mbias)[j] = o;
  }
}

// ------- shared GEMM core: C[m][n] = sum_k A[m][k]*Bm[n][k] -------
template <typename EpiFn>
__device__ __forceinline__
void gemm_core(const unsigned short* __restrict__ A,
               const unsigned short* __restrict__ Bm,
               int m0, int n0, EpiFn epi) {
  __shared__ unsigned short sA[128 * 64];
  __shared__ unsigned short sB[128 * 64];
  const int tid = threadIdx.x;
  const int l  = tid & 63;
  const int w  = tid >> 6;
  const int lm = l & 15;
  const int qd = l >> 4;
  const int wm = w & 1;
  const int wn = w >> 1;

  f32x4 acc[4][4];
#pragma unroll
  for (int i = 0; i < 4; ++i)
#pragma unroll
    for (int j = 0; j < 4; ++j) acc[i][j] = (f32x4){0.f, 0.f, 0.f, 0.f};

  for (int k0 = 0; k0 < EMBED; k0 += 64) {
#pragma unroll
    for (int i = 0; i < 4; ++i) {
      const int t = i * 256 + tid;
      const int r = t >> 3;
      const int c = (t & 7) ^ (r & 7);
      g2l16(A + (m0 + r) * EMBED + k0 + c * 8, &sA[(i * 256 + (w << 6)) * 8]);
      g2l16(Bm + (n0 + r) * EMBED + k0 + c * 8, &sB[(i * 256 + (w << 6)) * 8]);
    }
    __syncthreads();
#pragma unroll
    for (int kk = 0; kk < 2; ++kk) {
      bf16x8 af[4], bfr[4];
#pragma unroll
      for (int mi = 0; mi < 4; ++mi) {
        const int R = wm * 64 + mi * 16 + lm;
        const int ch = R * 8 + (((kk << 2) + qd) ^ (R & 7));
        af[mi] = *(const bf16x8*)&sA[ch * 8];
      }
#pragma unroll
      for (int ni = 0; ni < 4; ++ni) {
        const int R = wn * 64 + ni * 16 + lm;
        const int ch = R * 8 + (((kk << 2) + qd) ^ (R & 7));
        bfr[ni] = *(const bf16x8*)&sB[ch * 8];
      }
#pragma unroll
      for (int mi = 0; mi < 4; ++mi)
#pragma unroll
        for (int ni = 0; ni < 4; ++ni)
          acc[mi][ni] = __builtin_amdgcn_mfma_f32_16x16x32_bf16(
              af[mi], bfr[ni], acc[mi][ni], 0, 0, 0);
    }
    __syncthreads();
  }

#pragma unroll
  for (int mi = 0; mi < 4; ++mi)
#pragma unroll
    for (int ni = 0; ni < 4; ++ni) {
      const int mb = m0 + wm * 64 + mi * 16 + qd * 4;  // rows mb..mb+3
      const int n  = n0 + wn * 64 + ni * 16 + lm;
      epi(acc[mi][ni], mb, n);
    }
}

// supertile decode for L2 locality: 16 consecutive blocks = 2a x 8b tile grp
__device__ __forceinline__ void decode_tile(int flat, int& a0, int& b0) {
  const int sub = flat & 15;
  const int g = flat >> 4;           // 0..15
  a0 = ((g >> 2) * 2 + (sub >> 3));  // 0..7  (feature dim / 128)
  b0 = ((g & 3) * 8 + (sub & 7));    // 0..31 (token dim / 128)
}

// ------- fused Q/K/V projection -------
// z=0: Q = Wq·x^T ->(b,h,s,d) bf16, pre-scaled by (1/8)*log2(e)
// z=1: K = Wk·x^T ->(b,h,s,d) bf16
// z=2: V = x·Wv^T ->(b,h,d,s') fp16, key columns PERMUTED within each
//      32-key block (newcol = qd*8 + j*4 + r for key = j*16+qd*4+r) so the
//      attention PV A-frags of two j-tiles live in one 16B chunk.
__global__ __launch_bounds__(256)
void gemm_qkv(const unsigned short* __restrict__ xb,
              const unsigned short* __restrict__ Wqb,
              const unsigned short* __restrict__ Wkb,
              const unsigned short* __restrict__ Wvb,
              const float* __restrict__ bq, const float* __restrict__ bk,
              const float* __restrict__ bv,
              unsigned short* __restrict__ Qb, unsigned short* __restrict__ Kb,
              unsigned short* __restrict__ VTb) {
  const int z = blockIdx.y;
  int a0, b0;
  decode_tile(blockIdx.x, a0, b0);
  if (z < 2) {
    const unsigned short* A = z ? Wkb : Wqb;
    const float* bias = z ? bk : bq;
    unsigned short* O = z ? Kb : Qb;
    const float scale = z ? 1.0f : 0.125f * 1.4426950408889634f;
    gemm_core(A, xb, a0 * 128, b0 * 128, [&](const f32x4& v, int mb, int n) {
      const float4 bvv = *(const float4*)&bias[mb];
      const int h = mb >> 6, d0 = mb & 63;
      const int b = n >> 11, s = n & 2047;
      ushort4 u;
      u.x = f2bf((v.x + bvv.x) * scale); u.y = f2bf((v.y + bvv.y) * scale);
      u.z = f2bf((v.z + bvv.z) * scale); u.w = f2bf((v.w + bvv.w) * scale);
      *(ushort4*)&O[(((b * NHEAD + h) * SS) + s) * HDIM + d0] = u;
    });
  } else {
    gemm_core(xb, Wvb, b0 * 128, a0 * 128, [&](const f32x4& v, int mb, int n) {
      const float bvv = bv[n];
      const int b = mb >> 11, s = mb & 2047;   // s = key, ≡0 mod 4
      const int h = n >> 6, d = n & 63;
      // permute within 32-key block: key j*16+qd*4+r -> qd*8 + j*4 + r
      const int col = (s & ~31) + ((s >> 2) & 3) * 8 + ((s >> 4) & 1) * 4;
      ushort4 u;
      u.x = f2h(v.x + bvv); u.y = f2h(v.y + bvv);
      u.z = f2h(v.z + bvv); u.w = f2h(v.w + bvv);
      *(ushort4*)&VTb[(((b * NHEAD + h) * HDIM) + d) * SS + col] = u;
    });
  }
}

// ------- output projection: fp32 out -------
__global__ __launch_bounds__(256)
void gemm_out(const unsigned short* __restrict__ Wob,
              const unsigned short* __restrict__ Ob,
              const float* __restrict__ bo, float* __restrict__ out) {
  int a0, b0;
  decode_tile(blockIdx.x, a0, b0);
  gemm_core(Wob, Ob, a0 * 128, b0 * 128, [&](const f32x4& v, int mb, int n) {
    const float4 bvv = *(const float4*)&bo[mb];
    float4 o;
    o.x = v.x + bvv.x; o.y = v.y + bvv.y; o.z = v.z + bvv.z; o.w = v.w + bvv.w;
    *(float4*)&out[n * EMBED + mb] = o;
  });
}

// ------- flash attention, key-split x3: 32 q/wave, partial (O,l) per split ----
// grid (16 qtiles, 16 heads, sp*2+b). Partials additive (no max-shift):
// O = sum P_i / sum l_i in combine_kernel. V reads are single ds_read_b128
// per j-PAIR (key-permuted VT layout) -> conflict-free LDS.
__global__ __launch_bounds__(256)
void attn_kernel(const unsigned short* __restrict__ Q,
                 const unsigned short* __restrict__ K,
                 const unsigned short* __restrict__ VT,
                 const float* __restrict__ mbias,
                 unsigned short* __restrict__ Op0,
                 unsigned short* __restrict__ Op1,
                 unsigned short* __restrict__ Op2,
                 float* __restrict__ Lpart) {
  __shared__ unsigned short sK[64 * 64];  // bf16, row=key, chunk-swizzled
  __shared__ unsigned short sV[64 * 64];  // fp16, row=dim, chunk-swizzled
  const int tid = threadIdx.x;
  const int l = tid & 63, w = tid >> 6;
  const int lm = l & 15, qd = l >> 4;
  const int b = blockIdx.z & 1, sp = blockIdx.z >> 1, h = blockIdx.y;
  const int q0 = blockIdx.x * 128 + w * 32;  // wave: q0 .. q0+31
  const unsigned short* Qh = Q + ((b * NHEAD + h) * SS) * HDIM;
  const unsigned short* Kh = K + ((b * NHEAD + h) * SS) * HDIM;
  const unsigned short* Vh = VT + ((b * NHEAD + h) * HDIM) * SS;
  const float* mb = mbias + b * SS;
  unsigned short* Op = (sp == 0) ? Op0 : (sp == 1) ? Op1 : Op2;
  float* Lp = Lpart + sp * (BB * NHEAD * SS);

  bf16x8 qf[2][2];
#pragma unroll
  for (int g = 0; g < 2; ++g) {
    qf[g][0] = *(const bf16x8*)&Qh[(q0 + g * 16 + lm) * HDIM + qd * 8];
    qf[g][1] = *(const bf16x8*)&Qh[(q0 + g * 16 + lm) * HDIM + 32 + qd * 8];
  }

  f32x4 Od[2][4];
#pragma unroll
  for (int g = 0; g < 2; ++g)
#pragma unroll
    for (int i = 0; i < 4; ++i) Od[g][i] = (f32x4){0.f, 0.f, 0.f, 0.f};
  float lsum[2] = {0.f, 0.f};

  const int k0 = (sp == 0) ? 0 : (sp == 1) ? 704 : 1408;
  const int k1 = (sp == 0) ? 704 : (sp == 1) ? 1408 : 2048;
  for (int kb = k0; kb < k1; kb += 64) {
#pragma unroll
    for (int i = 0; i < 2; ++i) {
      const int t = i * 256 + tid;
      const int r = t >> 3;
      const int c = (t & 7) ^ (r & 7);
      g2l16(Kh + (kb + r) * HDIM + c * 8, &sK[(i * 256 + (w << 6)) * 8]);
      g2l16(Vh + r * SS + kb + c * 8, &sV[(i * 256 + (w << 6)) * 8]);
    }
    __syncthreads();

    // S^T per j-tile: C row = key (j*16+qd*4+r), col = q (lm). K-frags read
    // ONCE, used by both q-groups. Mask enters as the accumulator init.
    f16x4 pf[2][4];
#pragma unroll
    for (int j = 0; j < 4; ++j) {
      const int R = j * 16 + lm;
      const bf16x8 k0f = *(const bf16x8*)&sK[(R * 8 + (qd ^ (lm & 7))) * 8];
      const bf16x8 k1f = *(const bf16x8*)&sK[(R * 8 + ((4 + qd) ^ (lm & 7))) * 8];
      const float4 bj = *(const float4*)&mb[kb + j * 16 + qd * 4];
      const f32x4 binit = (f32x4){bj.x, bj.y, bj.z, bj.w};
#pragma unroll
      for (int g = 0; g < 2; ++g) {
        f32x4 t0 = binit;
        t0 = __builtin_amdgcn_mfma_f32_16x16x32_bf16(k0f, qf[g][0], t0, 0, 0, 0);
        t0 = __builtin_amdgcn_mfma_f32_16x16x32_bf16(k1f, qf[g][1], t0, 0, 0, 0);
        const float p0 = EXP2(t0[0]);
        const float p1 = EXP2(t0[1]);
        const float p2 = EXP2(t0[2]);
        const float p3 = EXP2(t0[3]);
        lsum[g] += (p0 + p1) + (p2 + p3);
        union { hf16x2 v[2]; f16x4 f; } pk;
        pk.v[0] = __builtin_amdgcn_cvt_pkrtz(p0, p1);
        pk.v[1] = __builtin_amdgcn_cvt_pkrtz(p2, p3);
        pf[g][j] = pk.f;
      }
    }

    // O^T += V-frag x P-frag; one b128 per j-PAIR (permuted VT layout:
    // chunk (p*4+qd)^(lm&7) = [frag j=2p | frag j=2p+1] for keys qd*4..+3).
#pragma unroll
    for (int dt = 0; dt < 4; ++dt) {
      const int row = dt * 16 + lm;
#pragma unroll
      for (int p = 0; p < 2; ++p) {
        const int ch = (p * 4 + qd) ^ (lm & 7);
        const f16x8 v8 = *(const f16x8*)&sV[row * 64 + ch * 8];
        const f16x4 vlo = __builtin_shufflevector(v8, v8, 0, 1, 2, 3);
        const f16x4 vhi = __builtin_shufflevector(v8, v8, 4, 5, 6, 7);
#pragma unroll
        for (int g = 0; g < 2; ++g) {
          Od[g][dt] = __builtin_amdgcn_mfma_f32_16x16x16f16(vlo, pf[g][2 * p],
                                                            Od[g][dt], 0, 0, 0);
          Od[g][dt] = __builtin_amdgcn_mfma_f32_16x16x16f16(vhi, pf[g][2 * p + 1],
                                                            Od[g][dt], 0, 0, 0);
        }
      }
    }
    __syncthreads();
  }

#pragma unroll
  for (int g = 0; g < 2; ++g) {
    float ls = lsum[g];
    ls += __shfl_xor(ls, 16);
    ls += __shfl_xor(ls, 32);
    if (qd == 0) Lp[(b * NHEAD + h) * SS + q0 + g * 16 + lm] = ls;
    // O^T C-layout: lane (qd,lm) holds q=lm(+g*16), dims dt*16 + qd*4 + r
#pragma unroll
    for (int dt = 0; dt < 4; ++dt) {
      ushort4 u;
      u.x = f2bf(Od[g][dt][0]); u.y = f2bf(Od[g][dt][1]);
      u.z = f2bf(Od[g][dt][2]); u.w = f2bf(Od[g][dt][3]);
      *(ushort4*)&Op[(b * SS + q0 + g * 16 + lm) * EMBED + h * HDIM +
                     dt * 16 + qd * 4] = u;
    }
  }
}

// ------- combine: Ob = (P0+P1+P2)/(l0+l1+l2), written IN-PLACE into Op0 ----
__global__ __launch_bounds__(256)
void combine_kernel(unsigned short* __restrict__ Op0,
                    const unsigned short* __restrict__ Op1,
                    const unsigned short* __restrict__ Op2,
                    const float* __restrict__ Lpart) {
  const int i = blockIdx.x * 256 + threadIdx.x;  // per 8 elems
  const int base = i * 8;
  const int token = base >> 10;       // 0..4095
  const int h = (base >> 6) & 15;
  const int b = token >> 11, q = token & 2047;
  const int lidx = (b * NHEAD + h) * SS + q;
  const int LN = BB * NHEAD * SS;
  const float ls = Lpart[lidx] + Lpart[LN + lidx] + Lpart[2 * LN + lidx];
  const float rinv = 1.f / ls;
#pragma unroll
  for (int k = 0; k < 2; ++k) {
    const ushort4 a = *(const ushort4*)&Op0[base + k * 4];
    const ushort4 c = *(const ushort4*)&Op1[base + k * 4];
    const ushort4 d = *(const ushort4*)&Op2[base + k * 4];
    ushort4 o;
    o.x = f2bf((bf2f(a.x) + bf2f(c.x) + bf2f(d.x)) * rinv);
    o.y = f2bf((bf2f(a.y) + bf2f(c.y) + bf2f(d.y)) * rinv);
    o.z = f2bf((bf2f(a.z) + bf2f(c.z) + bf2f(d.z)) * rinv);
    o.w = f2bf((bf2f(a.w) + bf2f(c.w) + bf2f(d.w)) * rinv);
    *(ushort4*)&Op0[base + k * 4] = o;
  }
}

extern "C" void kernel_launch(void* const* d_in, const int* in_sizes, int n_in,
                              void* d_out, int out_size, void* d_ws, size_t ws_size,
                              hipStream_t stream) {
  const float* x  = (const float*)d_in[0];
  const int* mask = (const int*)d_in[1];
  const float* Wq = (const float*)d_in[2];
  const float* bq = (const float*)d_in[3];
  const float* Wk = (const float*)d_in[4];
  const float* bk = (const float*)d_in[5];
  const float* Wv = (const float*)d_in[6];
  const float* bv = (const float*)d_in[7];
  const float* Wo = (const float*)d_in[8];
  const float* bo = (const float*)d_in[9];
  float* out = (float*)d_out;

  char* ws = (char*)d_ws;
  const size_t MB = 1024 * 1024;
  // lifetimes: xb [0,8MB) dead after gemm_qkv -> Opart2 reuses it.
  // Opart0 [41,49) doubles as Ob (combine writes in-place, gemm_out reads).
  unsigned short* xb  = (unsigned short*)(ws);
  unsigned short* Wqb = (unsigned short*)(ws + 8 * MB);
  unsigned short* Wkb = (unsigned short*)(ws + 10 * MB);
  unsigned short* Wvb = (unsigned short*)(ws + 12 * MB);
  unsigned short* Wob = (unsigned short*)(ws + 14 * MB);   // live till gemm_out
  unsigned short* Qb  = (unsigned short*)(ws + 16 * MB);
  unsigned short* Kb  = (unsigned short*)(ws + 24 * MB);
  unsigned short* VTb = (unsigned short*)(ws + 32 * MB);
  float* mbb   = (float*)(ws + 40 * MB);                   // 16KB
  float* Lpart = (float*)(ws + 40 * MB + 64 * 1024);       // 3 x 256KB
  unsigned short* Op0 = (unsigned short*)(ws + 41 * MB);   // 8MB, becomes Ob
  unsigned short* Op1 = (unsigned short*)(ws + 49 * MB);   // 8MB (end 57MB)
  unsigned short* Op2 = (unsigned short*)(ws);             // aliases dead xb

  cvt5_kernel<<<8196, 256, 0, stream>>>(x, Wq, Wk, Wv, Wo, mask,
                                        xb, Wqb, Wkb, Wvb, Wob, mbb);
  gemm_qkv<<<dim3(256, 3), 256, 0, stream>>>(xb, Wqb, Wkb, Wvb, bq, bk, bv,
                                             Qb, Kb, VTb);
  attn_kernel<<<dim3(16, 16, 6), 256, 0, stream>>>(Qb, Kb, VTb, mbb,
                                                   Op0, Op1, Op2, Lpart);
  combine_kernel<<<2048, 256, 0, stream>>>(Op0, Op1, Op2, Lpart);
  gemm_out<<<256, 256, 0, stream>>>(Wob, Op0, bo, out);
}

// Round 8
// 220.252 us; speedup vs baseline: 1.0158x; 1.0158x over previous
//
#include <hip/hip_runtime.h>

#define EMBED 1024
#define NHEAD 16
#define HDIM  64
#define BB    2
#define SS    2048

typedef __bf16 bf16x8 __attribute__((ext_vector_type(8)));
typedef float  f32x4  __attribute__((ext_vector_type(4)));
typedef _Float16 f16x4 __attribute__((ext_vector_type(4)));
typedef _Float16 f16x8 __attribute__((ext_vector_type(8)));
typedef __fp16 hf16x2 __attribute__((ext_vector_type(2)));

#if defined(__has_builtin)
#if __has_builtin(__builtin_amdgcn_exp2f)
#define EXP2(x) __builtin_amdgcn_exp2f(x)
#else
#define EXP2(x) exp2f(x)
#endif
#else
#define EXP2(x) exp2f(x)
#endif

__device__ __forceinline__ unsigned short f2bf(float f) {
  union { float f; unsigned u; } v; v.f = f;
  unsigned r = v.u + 0x7fffu + ((v.u >> 16) & 1u);
  return (unsigned short)(r >> 16);
}

__device__ __forceinline__ float bf2f(unsigned short u) {
  union { unsigned u; float f; } v; v.u = ((unsigned)u) << 16;
  return v.f;
}

__device__ __forceinline__ unsigned short f2h(float f) {
  union { _Float16 h; unsigned short u; } t;
  t.h = (_Float16)f;
  return t.u;
}

__device__ __forceinline__ void g2l16(const unsigned short* g, unsigned short* l) {
  __builtin_amdgcn_global_load_lds(
      (const __attribute__((address_space(1))) unsigned int*)g,
      (__attribute__((address_space(3))) unsigned int*)l, 16, 0, 0);
}

// ------- fused fp32->bf16 convert of x + 4 weights, + maskbias build -------
__global__ __launch_bounds__(256)
void cvt5_kernel(const float* __restrict__ x,  const float* __restrict__ Wq,
                 const float* __restrict__ Wk, const float* __restrict__ Wv,
                 const float* __restrict__ Wo, const int* __restrict__ mask,
                 unsigned short* __restrict__ xb,  unsigned short* __restrict__ Wqb,
                 unsigned short* __restrict__ Wkb, unsigned short* __restrict__ Wvb,
                 unsigned short* __restrict__ Wob, float* __restrict__ mbias) {
  const int i = blockIdx.x * 256 + threadIdx.x;
  if (i < (1 << 21)) {
    const float* src;
    unsigned short* dst;
    int j;
    if (i < (1 << 20)) {
      src = x; dst = xb; j = i;
    } else {
      const int t = i - (1 << 20);
      const int r = t >> 18;
      j = t & ((1 << 18) - 1);
      src = (r == 0) ? Wq : (r == 1) ? Wk : (r == 2) ? Wv : Wo;
      dst = (r == 0) ? Wqb : (r == 1) ? Wkb : (r == 2) ? Wvb : Wob;
    }
    const float4 f = ((const float4*)src)[j];
    ushort4 u;
    u.x = f2bf(f.x); u.y = f2bf(f.y); u.z = f2bf(f.z); u.w = f2bf(f.w);
    ((ushort4*)dst)[j] = u;
  } else {
    const int j = i - (1 << 21);  // 0..1023 int4 groups of mask
    const int4 m = ((const int4*)mask)[j];
    float4 o;
    o.x = m.x ? 0.f : -1e30f; o.y = m.y ? 0.f : -1e30f;
    o.z = m.z ? 0.f : -1e30f; o.w = m.w ? 0.f : -1e30f;
    ((float4*)mbias)[j] = o;
  }
}

// ------- shared GEMM core: C[m][n] = sum_k A[m][k]*Bm[n][k] -------
template <typename EpiFn>
__device__ __forceinline__
void gemm_core(const unsigned short* __restrict__ A,
               const unsigned short* __restrict__ Bm,
               int m0, int n0, EpiFn epi) {
  __shared__ unsigned short sA[128 * 64];
  __shared__ unsigned short sB[128 * 64];
  const int tid = threadIdx.x;
  const int l  = tid & 63;
  const int w  = tid >> 6;
  const int lm = l & 15;
  const int qd = l >> 4;
  const int wm = w & 1;
  const int wn = w >> 1;

  f32x4 acc[4][4];
#pragma unroll
  for (int i = 0; i < 4; ++i)
#pragma unroll
    for (int j = 0; j < 4; ++j) acc[i][j] = (f32x4){0.f, 0.f, 0.f, 0.f};

  for (int k0 = 0; k0 < EMBED; k0 += 64) {
#pragma unroll
    for (int i = 0; i < 4; ++i) {
      const int t = i * 256 + tid;
      const int r = t >> 3;
      const int c = (t & 7) ^ (r & 7);
      g2l16(A + (m0 + r) * EMBED + k0 + c * 8, &sA[(i * 256 + (w << 6)) * 8]);
      g2l16(Bm + (n0 + r) * EMBED + k0 + c * 8, &sB[(i * 256 + (w << 6)) * 8]);
    }
    __syncthreads();
#pragma unroll
    for (int kk = 0; kk < 2; ++kk) {
      bf16x8 af[4], bfr[4];
#pragma unroll
      for (int mi = 0; mi < 4; ++mi) {
        const int R = wm * 64 + mi * 16 + lm;
        const int ch = R * 8 + (((kk << 2) + qd) ^ (R & 7));
        af[mi] = *(const bf16x8*)&sA[ch * 8];
      }
#pragma unroll
      for (int ni = 0; ni < 4; ++ni) {
        const int R = wn * 64 + ni * 16 + lm;
        const int ch = R * 8 + (((kk << 2) + qd) ^ (R & 7));
        bfr[ni] = *(const bf16x8*)&sB[ch * 8];
      }
#pragma unroll
      for (int mi = 0; mi < 4; ++mi)
#pragma unroll
        for (int ni = 0; ni < 4; ++ni)
          acc[mi][ni] = __builtin_amdgcn_mfma_f32_16x16x32_bf16(
              af[mi], bfr[ni], acc[mi][ni], 0, 0, 0);
    }
    __syncthreads();
  }

#pragma unroll
  for (int mi = 0; mi < 4; ++mi)
#pragma unroll
    for (int ni = 0; ni < 4; ++ni) {
      const int mb = m0 + wm * 64 + mi * 16 + qd * 4;  // rows mb..mb+3
      const int n  = n0 + wn * 64 + ni * 16 + lm;
      epi(acc[mi][ni], mb, n);
    }
}

// supertile decode for L2 locality: 16 consecutive blocks = 2a x 8b tile grp
__device__ __forceinline__ void decode_tile(int flat, int& a0, int& b0) {
  const int sub = flat & 15;
  const int g = flat >> 4;           // 0..15
  a0 = ((g >> 2) * 2 + (sub >> 3));  // 0..7  (feature dim / 128)
  b0 = ((g & 3) * 8 + (sub & 7));    // 0..31 (token dim / 128)
}

// ------- fused Q/K/V projection -------
// z=0: Q = Wq·x^T ->(b,h,s,d) bf16, pre-scaled by (1/8)*log2(e)
// z=1: K = Wk·x^T ->(b,h,s,d) bf16
// z=2: V = x·Wv^T ->(b,h,d,s') fp16, key columns PERMUTED within each
//      32-key block (key j*16+qd*4+r -> qd*8+j*4+r) so the attention PV
//      A-frags of two j-tiles live in one 16B chunk (conflict-free b128).
__global__ __launch_bounds__(256)
void gemm_qkv(const unsigned short* __restrict__ xb,
              const unsigned short* __restrict__ Wqb,
              const unsigned short* __restrict__ Wkb,
              const unsigned short* __restrict__ Wvb,
              const float* __restrict__ bq, const float* __restrict__ bk,
              const float* __restrict__ bv,
              unsigned short* __restrict__ Qb, unsigned short* __restrict__ Kb,
              unsigned short* __restrict__ VTb) {
  const int z = blockIdx.y;
  int a0, b0;
  decode_tile(blockIdx.x, a0, b0);
  if (z < 2) {
    const unsigned short* A = z ? Wkb : Wqb;
    const float* bias = z ? bk : bq;
    unsigned short* O = z ? Kb : Qb;
    const float scale = z ? 1.0f : 0.125f * 1.4426950408889634f;
    gemm_core(A, xb, a0 * 128, b0 * 128, [&](const f32x4& v, int mb, int n) {
      const float4 bvv = *(const float4*)&bias[mb];
      const int h = mb >> 6, d0 = mb & 63;
      const int b = n >> 11, s = n & 2047;
      ushort4 u;
      u.x = f2bf((v.x + bvv.x) * scale); u.y = f2bf((v.y + bvv.y) * scale);
      u.z = f2bf((v.z + bvv.z) * scale); u.w = f2bf((v.w + bvv.w) * scale);
      *(ushort4*)&O[(((b * NHEAD + h) * SS) + s) * HDIM + d0] = u;
    });
  } else {
    gemm_core(xb, Wvb, b0 * 128, a0 * 128, [&](const f32x4& v, int mb, int n) {
      const float bvv = bv[n];
      const int b = mb >> 11, s = mb & 2047;   // s = key, ≡0 mod 4
      const int h = n >> 6, d = n & 63;
      const int col = (s & ~31) + ((s >> 2) & 3) * 8 + ((s >> 4) & 1) * 4;
      ushort4 u;
      u.x = f2h(v.x + bvv); u.y = f2h(v.y + bvv);
      u.z = f2h(v.z + bvv); u.w = f2h(v.w + bvv);
      *(ushort4*)&VTb[(((b * NHEAD + h) * HDIM) + d) * SS + col] = u;
    });
  }
}

// ------- output projection: fp32 out -------
__global__ __launch_bounds__(256)
void gemm_out(const unsigned short* __restrict__ Wob,
              const unsigned short* __restrict__ Ob,
              const float* __restrict__ bo, float* __restrict__ out) {
  int a0, b0;
  decode_tile(blockIdx.x, a0, b0);
  gemm_core(Wob, Ob, a0 * 128, b0 * 128, [&](const f32x4& v, int mb, int n) {
    const float4 bvv = *(const float4*)&bo[mb];
    float4 o;
    o.x = v.x + bvv.x; o.y = v.y + bvv.y; o.z = v.z + bvv.z; o.w = v.w + bvv.w;
    *(float4*)&out[n * EMBED + mb] = o;
  });
}

// ------- flash attention, key-split x2, DOUBLE-BUFFERED staging ----------
// Block = 128 q (4 waves x 32). grid (16 qtiles, 16 heads, sp*2+b).
// Per iter: one __syncthreads; tile i+1 is prefetched into the other LDS
// buffer right after the barrier, so the global->LDS latency is hidden
// behind the compute of tile i (the R7 structure exposed it every iter).
// Partials additive (no max-shift): O = (P0+P1)/(l0+l1) in combine_kernel.
__global__ __launch_bounds__(256)
void attn_kernel(const unsigned short* __restrict__ Q,
                 const unsigned short* __restrict__ K,
                 const unsigned short* __restrict__ VT,
                 const float* __restrict__ mbias,
                 unsigned short* __restrict__ Op0,
                 unsigned short* __restrict__ Op1,
                 float* __restrict__ Lpart) {
  __shared__ unsigned short sK[2][64 * 64];  // bf16, row=key, chunk-swizzled
  __shared__ unsigned short sV[2][64 * 64];  // fp16, row=dim, chunk-swizzled
  __shared__ float sM[1024];                 // maskbias for this split
  const int tid = threadIdx.x;
  const int l = tid & 63, w = tid >> 6;
  const int lm = l & 15, qd = l >> 4;
  const int b = blockIdx.z & 1, sp = blockIdx.z >> 1, h = blockIdx.y;
  const int q0 = blockIdx.x * 128 + w * 32;  // wave: q0 .. q0+31
  const unsigned short* Qh = Q + ((b * NHEAD + h) * SS) * HDIM;
  const unsigned short* Kh = K + ((b * NHEAD + h) * SS) * HDIM;
  const unsigned short* Vh = VT + ((b * NHEAD + h) * HDIM) * SS;
  const int k0 = sp * (SS / 2);
  unsigned short* Op = sp ? Op1 : Op0;
  float* Lp = Lpart + sp * (BB * NHEAD * SS);

  // stage maskbias for this split (1024 floats) into LDS
  *(float4*)&sM[tid * 4] = *(const float4*)&mbias[b * SS + k0 + tid * 4];

  bf16x8 qf[2][2];
#pragma unroll
  for (int g = 0; g < 2; ++g) {
    qf[g][0] = *(const bf16x8*)&Qh[(q0 + g * 16 + lm) * HDIM + qd * 8];
    qf[g][1] = *(const bf16x8*)&Qh[(q0 + g * 16 + lm) * HDIM + 32 + qd * 8];
  }

  f32x4 Od[2][4];
#pragma unroll
  for (int g = 0; g < 2; ++g)
#pragma unroll
    for (int i = 0; i < 4; ++i) Od[g][i] = (f32x4){0.f, 0.f, 0.f, 0.f};
  float lsum[2] = {0.f, 0.f};

  auto stage = [&](int kb, int buf) {
#pragma unroll
    for (int i = 0; i < 2; ++i) {
      const int t = i * 256 + tid;
      const int r = t >> 3;
      const int c = (t & 7) ^ (r & 7);
      g2l16(Kh + (kb + r) * HDIM + c * 8, &sK[buf][(i * 256 + (w << 6)) * 8]);
      g2l16(Vh + r * SS + kb + c * 8, &sV[buf][(i * 256 + (w << 6)) * 8]);
    }
  };

  const int nIt = (SS / 2) / 64;  // 16
  stage(k0, 0);
  for (int it = 0; it < nIt; ++it) {
    __syncthreads();  // implicit vmcnt(0)+lgkmcnt(0): own loads for tile it done
    if (it + 1 < nIt) stage(k0 + (it + 1) * 64, (it + 1) & 1);
    const unsigned short* bK = sK[it & 1];
    const unsigned short* bV = sV[it & 1];
    const int mof = it * 64;

    // S^T per j-tile: C row = key (j*16+qd*4+r), col = q (lm). K-frags read
    // ONCE, used by both q-groups. Mask enters as the accumulator init.
    f16x4 pf[2][4];
#pragma unroll
    for (int j = 0; j < 4; ++j) {
      const int R = j * 16 + lm;
      const bf16x8 k0f = *(const bf16x8*)&bK[(R * 8 + (qd ^ (lm & 7))) * 8];
      const bf16x8 k1f = *(const bf16x8*)&bK[(R * 8 + ((4 + qd) ^ (lm & 7))) * 8];
      const f32x4 binit = *(const f32x4*)&sM[mof + j * 16 + qd * 4];
#pragma unroll
      for (int g = 0; g < 2; ++g) {
        f32x4 t0 = binit;
        t0 = __builtin_amdgcn_mfma_f32_16x16x32_bf16(k0f, qf[g][0], t0, 0, 0, 0);
        t0 = __builtin_amdgcn_mfma_f32_16x16x32_bf16(k1f, qf[g][1], t0, 0, 0, 0);
        const float p0 = EXP2(t0[0]);
        const float p1 = EXP2(t0[1]);
        const float p2 = EXP2(t0[2]);
        const float p3 = EXP2(t0[3]);
        lsum[g] += (p0 + p1) + (p2 + p3);
        union { hf16x2 v[2]; f16x4 f; } pk;
        pk.v[0] = __builtin_amdgcn_cvt_pkrtz(p0, p1);
        pk.v[1] = __builtin_amdgcn_cvt_pkrtz(p2, p3);
        pf[g][j] = pk.f;
      }
    }

    // O^T += V-frag x P-frag; one b128 per j-PAIR (permuted VT layout:
    // chunk (p*4+qd)^(lm&7) = [frag j=2p | frag j=2p+1] for keys qd*4..+3).
#pragma unroll
    for (int dt = 0; dt < 4; ++dt) {
      const int row = dt * 16 + lm;
#pragma unroll
      for (int p = 0; p < 2; ++p) {
        const int ch = (p * 4 + qd) ^ (lm & 7);
        const f16x8 v8 = *(const f16x8*)&bV[row * 64 + ch * 8];
        const f16x4 vlo = __builtin_shufflevector(v8, v8, 0, 1, 2, 3);
        const f16x4 vhi = __builtin_shufflevector(v8, v8, 4, 5, 6, 7);
#pragma unroll
        for (int g = 0; g < 2; ++g) {
          Od[g][dt] = __builtin_amdgcn_mfma_f32_16x16x16f16(vlo, pf[g][2 * p],
                                                            Od[g][dt], 0, 0, 0);
          Od[g][dt] = __builtin_amdgcn_mfma_f32_16x16x16f16(vhi, pf[g][2 * p + 1],
                                                            Od[g][dt], 0, 0, 0);
        }
      }
    }
  }

#pragma unroll
  for (int g = 0; g < 2; ++g) {
    float ls = lsum[g];
    ls += __shfl_xor(ls, 16);
    ls += __shfl_xor(ls, 32);
    if (qd == 0) Lp[(b * NHEAD + h) * SS + q0 + g * 16 + lm] = ls;
    // O^T C-layout: lane (qd,lm) holds q=lm(+g*16), dims dt*16 + qd*4 + r
#pragma unroll
    for (int dt = 0; dt < 4; ++dt) {
      ushort4 u;
      u.x = f2bf(Od[g][dt][0]); u.y = f2bf(Od[g][dt][1]);
      u.z = f2bf(Od[g][dt][2]); u.w = f2bf(Od[g][dt][3]);
      *(ushort4*)&Op[(b * SS + q0 + g * 16 + lm) * EMBED + h * HDIM +
                     dt * 16 + qd * 4] = u;
    }
  }
}

// ------- combine: Ob = (P0+P1)/(l0+l1), written IN-PLACE into Op0 ----
__global__ __launch_bounds__(256)
void combine_kernel(unsigned short* __restrict__ Op0,
                    const unsigned short* __restrict__ Op1,
                    const float* __restrict__ Lpart) {
  const int i = blockIdx.x * 256 + threadIdx.x;  // per 8 elems
  const int base = i * 8;
  const int token = base >> 10;       // 0..4095
  const int h = (base >> 6) & 15;
  const int b = token >> 11, q = token & 2047;
  const int lidx = (b * NHEAD + h) * SS + q;
  const int LN = BB * NHEAD * SS;
  const float ls = Lpart[lidx] + Lpart[LN + lidx];
  const float rinv = 1.f / ls;
#pragma unroll
  for (int k = 0; k < 2; ++k) {
    const ushort4 a = *(const ushort4*)&Op0[base + k * 4];
    const ushort4 c = *(const ushort4*)&Op1[base + k * 4];
    ushort4 o;
    o.x = f2bf((bf2f(a.x) + bf2f(c.x)) * rinv);
    o.y = f2bf((bf2f(a.y) + bf2f(c.y)) * rinv);
    o.z = f2bf((bf2f(a.z) + bf2f(c.z)) * rinv);
    o.w = f2bf((bf2f(a.w) + bf2f(c.w)) * rinv);
    *(ushort4*)&Op0[base + k * 4] = o;
  }
}

extern "C" void kernel_launch(void* const* d_in, const int* in_sizes, int n_in,
                              void* d_out, int out_size, void* d_ws, size_t ws_size,
                              hipStream_t stream) {
  const float* x  = (const float*)d_in[0];
  const int* mask = (const int*)d_in[1];
  const float* Wq = (const float*)d_in[2];
  const float* bq = (const float*)d_in[3];
  const float* Wk = (const float*)d_in[4];
  const float* bk = (const float*)d_in[5];
  const float* Wv = (const float*)d_in[6];
  const float* bv = (const float*)d_in[7];
  const float* Wo = (const float*)d_in[8];
  const float* bo = (const float*)d_in[9];
  float* out = (float*)d_out;

  char* ws = (char*)d_ws;
  const size_t MB = 1024 * 1024;
  // lifetimes: Opart0 [41,49) doubles as Ob (combine writes in-place).
  unsigned short* xb  = (unsigned short*)(ws);
  unsigned short* Wqb = (unsigned short*)(ws + 8 * MB);
  unsigned short* Wkb = (unsigned short*)(ws + 10 * MB);
  unsigned short* Wvb = (unsigned short*)(ws + 12 * MB);
  unsigned short* Wob = (unsigned short*)(ws + 14 * MB);   // live till gemm_out
  unsigned short* Qb  = (unsigned short*)(ws + 16 * MB);
  unsigned short* Kb  = (unsigned short*)(ws + 24 * MB);
  unsigned short* VTb = (unsigned short*)(ws + 32 * MB);
  float* mbb   = (float*)(ws + 40 * MB);                   // 16KB
  float* Lpart = (float*)(ws + 40 * MB + 64 * 1024);       // 2 x 256KB
  unsigned short* Op0 = (unsigned short*)(ws + 41 * MB);   // 8MB, becomes Ob
  unsigned short* Op1 = (unsigned short*)(ws + 49 * MB);   // 8MB (end 57MB)

  cvt5_kernel<<<8196, 256, 0, stream>>>(x, Wq, Wk, Wv, Wo, mask,
                                        xb, Wqb, Wkb, Wvb, Wob, mbb);
  gemm_qkv<<<dim3(256, 3), 256, 0, stream>>>(xb, Wqb, Wkb, Wvb, bq, bk, bv,
                                             Qb, Kb, VTb);
  attn_kernel<<<dim3(16, 16, 4), 256, 0, stream>>>(Qb, Kb, VTb, mbb,
                                                   Op0, Op1, Lpart);
  combine_kernel<<<2048, 256, 0, stream>>>(Op0, Op1, Lpart);
  gemm_out<<<256, 256, 0, stream>>>(Wob, Op0, bo, out);
}